// Round 1
// baseline (99.994 us; speedup 1.0000x reference)
//
#include <hip/hip_runtime.h>
#include <stdint.h>

#define B 4
#define N 16384
#define S 2048
#define C 64
#define K 64
#define OC 66
#define R2 0.01f

// ---------------------------------------------------------------------------
// Kernel 1: transpose features (B,C,N) -> ft (B,N,C) so that a selected
// point's 64 channels are contiguous (256B) for the gather.
// ---------------------------------------------------------------------------
__global__ __launch_bounds__(256) void transpose_kernel(const float* __restrict__ f,
                                                        float* __restrict__ ft) {
    __shared__ float tile[64 * 65];   // +1 pad -> conflict-free transpose read
    const int n0 = blockIdx.x * 64;
    const int b  = blockIdx.y;
    const int t  = threadIdx.x;

    const int nl = t & 63, cl = t >> 6;
    #pragma unroll
    for (int cc = cl; cc < 64; cc += 4) {
        // coalesced in nl (256B per wave)
        tile[cc * 65 + nl] = f[((size_t)b * C + cc) * N + n0 + nl];
    }
    __syncthreads();

    const int cl2 = t & 63, nl2 = t >> 6;
    #pragma unroll
    for (int nn = nl2; nn < 64; nn += 4) {
        // LDS read: bank (cl2+nn)%32 -> 2-way (free); store coalesced in cl2
        ft[((size_t)b * N + n0 + nn) * C + cl2] = tile[cl2 * 65 + nn];
    }
}

// ---------------------------------------------------------------------------
// Kernel 2: fused ball-query + group + concat. One 256-thread block per
// (b,s) query. Wave 0 does the ordered-selection scan (ballot + prefix
// popcount, early exit); then all 4 waves gather the 64x64 feature tile
// (coalesced via ft) into LDS and write out k-contiguous float4 stores.
// ---------------------------------------------------------------------------
template <bool USE_T>
__global__ __launch_bounds__(256) void qag_kernel(const float* __restrict__ xyz,
                                                  const float* __restrict__ new_xyz,
                                                  const float* __restrict__ feat,
                                                  const float* __restrict__ ft,
                                                  const int* __restrict__ pointsnum,
                                                  float* __restrict__ out) {
    __shared__ int   s_idx[K];
    __shared__ float tile[K * 65];    // tile[j][c], pitch 65

    const int blk = blockIdx.x;
    const int b   = blk >> 11;        // / S (S = 2048)
    const int s   = blk & (S - 1);
    const int t   = threadIdx.x;

    const float qx = new_xyz[((size_t)b * S + s) * 2 + 0];
    const float qy = new_xyz[((size_t)b * S + s) * 2 + 1];

    // ---- Phase 1: ball query (wave 0 only) ----
    if (t < 64) {
        const int lane = t;
        int pn = pointsnum[b];
        if (pn > N) pn = N;
        int cnt = 0;
        for (int base = 0; base < pn && cnt < K; base += 64) {
            const int i = base + lane;
            bool ok = false;
            if (i < pn) {
                const float2 p = *(const float2*)&xyz[((size_t)b * N + i) * 2];
                // match numpy f32 rounding exactly: no FMA contraction
                const float dx = __fsub_rn(qx, p.x);
                const float dy = __fsub_rn(qy, p.y);
                const float d2 = __fadd_rn(__fmul_rn(dx, dx), __fmul_rn(dy, dy));
                ok = d2 < R2;
            }
            const unsigned long long m = __ballot(ok);
            if (ok) {
                const int pos = cnt + __popcll(m & ((1ull << lane) - 1ull));
                if (pos < K) s_idx[pos] = i;
            }
            cnt += __popcll(m);
        }
        const int found = cnt < K ? cnt : K;
        const int first = (found > 0) ? s_idx[0] : 0;  // pad value (0 if none)
        if (lane >= found) s_idx[lane] = first;
    }
    __syncthreads();

    // ---- Phase 2a: gather 64 channels x 64 selected points into LDS ----
    {
        const int c  = t & 63;
        const int j0 = t >> 6;
        #pragma unroll
        for (int j = j0; j < K; j += 4) {
            const int id = s_idx[j];
            float v;
            if (USE_T) v = ft[((size_t)b * N + id) * C + c];          // 256B contiguous/row
            else       v = feat[((size_t)b * C + c) * N + id];        // fallback (strided)
            tile[j * 65 + c] = v;
        }
    }
    __syncthreads();

    // ---- Phase 2b: write out, float4 over k (16B/lane coalesced stores) ----
    {
        const int k0 = (t & 15) * 4;
        const int c0 = t >> 4;                       // 0..15
        const size_t obase = ((size_t)b * OC) * S * K + (size_t)s * K;
        #pragma unroll
        for (int cc = c0; cc < C; cc += 16) {
            float4 v;
            // bank = (4*(t&15) + 65*i + c0) % 32 -> 2 lanes/bank (free)
            v.x = tile[(k0 + 0) * 65 + cc];
            v.y = tile[(k0 + 1) * 65 + cc];
            v.z = tile[(k0 + 2) * 65 + cc];
            v.w = tile[(k0 + 3) * 65 + cc];
            *(float4*)&out[obase + (size_t)(2 + cc) * S * K + k0] = v;
        }
        // channels 0,1: grouped_xyz = xyz[id] - new_xyz[s]
        if (t < 64) {
            const int k  = t;
            const int id = s_idx[k];
            const float2 p = *(const float2*)&xyz[((size_t)b * N + id) * 2];
            out[obase + (size_t)0 * S * K + k] = p.x - qx;
            out[obase + (size_t)1 * S * K + k] = p.y - qy;
        }
    }
}

extern "C" void kernel_launch(void* const* d_in, const int* in_sizes, int n_in,
                              void* d_out, int out_size, void* d_ws, size_t ws_size,
                              hipStream_t stream) {
    const float* xyz       = (const float*)d_in[0];
    const float* new_xyz   = (const float*)d_in[1];
    const float* feat      = (const float*)d_in[2];
    const int*   pointsnum = (const int*)d_in[3];
    float*       out       = (float*)d_out;

    const size_t need = (size_t)B * N * C * sizeof(float);
    if (ws_size >= need) {
        float* ft = (float*)d_ws;
        transpose_kernel<<<dim3(N / 64, B), 256, 0, stream>>>(feat, ft);
        qag_kernel<true><<<B * S, 256, 0, stream>>>(xyz, new_xyz, feat, ft, pointsnum, out);
    } else {
        qag_kernel<false><<<B * S, 256, 0, stream>>>(xyz, new_xyz, feat, nullptr, pointsnum, out);
    }
}

// Round 2
// 60.729 us; speedup vs baseline: 1.6466x; 1.6466x over previous
//
#include <hip/hip_runtime.h>
#include <stdint.h>

#define B 4
#define N 16384
#define S 2048
#define C 64
#define K 64
#define OC 66
#define R2 0.01f

// ---------------------------------------------------------------------------
// Kernel 1: transpose features (B,C,N) -> ft (B,N,C) so that a selected
// point's 64 channels are contiguous (256B) for the gather.
// ---------------------------------------------------------------------------
__global__ __launch_bounds__(256) void transpose_kernel(const float* __restrict__ f,
                                                        float* __restrict__ ft) {
    __shared__ float tile[64 * 65];   // +1 pad -> conflict-free transpose read
    const int n0 = blockIdx.x * 64;
    const int b  = blockIdx.y;
    const int t  = threadIdx.x;

    const int nl = t & 63, cl = t >> 6;
    #pragma unroll
    for (int cc = cl; cc < 64; cc += 4) {
        tile[cc * 65 + nl] = f[((size_t)b * C + cc) * N + n0 + nl];
    }
    __syncthreads();

    const int cl2 = t & 63, nl2 = t >> 6;
    #pragma unroll
    for (int nn = nl2; nn < 64; nn += 4) {
        ft[((size_t)b * N + n0 + nn) * C + cl2] = tile[cl2 * 65 + nn];
    }
}

// ---------------------------------------------------------------------------
// Kernel 2: fused ball-query + group + concat. ONE WAVE PER QUERY.
// No __syncthreads, no cross-wave coupling: each wave scans for its own 64
// indices (super-chunks of 256 points = 4 loads in flight per latency step),
// then lane=k gathers its point's full 64-channel row (16x float4, 256B
// contiguous) and the block writes 66 channel-major 256B coalesced stores.
// ---------------------------------------------------------------------------
template <bool USE_T>
__global__ __launch_bounds__(256) void qag_kernel(const float* __restrict__ xyz,
                                                  const float* __restrict__ new_xyz,
                                                  const float* __restrict__ feat,
                                                  const float* __restrict__ ft,
                                                  const int* __restrict__ pointsnum,
                                                  float* __restrict__ out) {
    __shared__ int s_idx[4][K];       // per-wave index list (1 KB/block)

    const int t    = threadIdx.x;
    const int lane = t & 63;
    const int w    = t >> 6;
    const int q    = blockIdx.x * 4 + w;    // global query id = b*S + s
    const int b    = q >> 11;               // / S (S = 2048)
    const int s    = q & (S - 1);

    const float qx = new_xyz[(size_t)q * 2 + 0];
    const float qy = new_xyz[(size_t)q * 2 + 1];
    const float* __restrict__ xb = xyz + (size_t)b * N * 2;

    // ---- Phase 1: ordered ball-query scan (per-wave, pipelined 4 deep) ----
    int pn = pointsnum[b];
    pn = pn < 0 ? 0 : (pn > N ? N : pn);
    int cnt = 0;
    for (int base = 0; base < pn && cnt < K; base += 256) {
        float2 p[4];
        #pragma unroll
        for (int u = 0; u < 4; ++u) {
            int i  = base + u * 64 + lane;
            int ic = i < N ? i : N - 1;              // always-valid address
            p[u] = *(const float2*)&xb[(size_t)ic * 2];
        }
        #pragma unroll
        for (int u = 0; u < 4; ++u) {
            const int i = base + u * 64 + lane;
            bool ok = false;
            if (i < pn) {
                // match numpy f32 rounding exactly: no FMA contraction
                const float dx = __fsub_rn(qx, p[u].x);
                const float dy = __fsub_rn(qy, p[u].y);
                const float d2 = __fadd_rn(__fmul_rn(dx, dx), __fmul_rn(dy, dy));
                ok = d2 < R2;
            }
            const unsigned long long m = __ballot(ok);
            if (ok) {
                const int pos = cnt + __popcll(m & ((1ull << lane) - 1ull));
                if (pos < K) s_idx[w][pos] = i;
            }
            cnt += __popcll(m);
        }
    }
    const int found = cnt < K ? cnt : K;
    const int first = (found > 0) ? s_idx[w][0] : 0;   // pad value (0 if none)
    const int id    = (lane < found) ? s_idx[w][lane] : first;

    // ---- Phase 2: gather lane's point row + write channel-major stores ----
    const size_t SK    = (size_t)S * K;
    const size_t obase = ((size_t)b * OC) * SK + (size_t)s * K + lane;

    // grouped_xyz channels 0,1: xyz[id] - new_xyz[s]
    const float2 pxy = *(const float2*)&xb[(size_t)id * 2];

    float4 v[16];
    if (USE_T) {
        const float* __restrict__ row = ft + ((size_t)b * N + id) * C;
        #pragma unroll
        for (int g = 0; g < 16; ++g) v[g] = *(const float4*)&row[g * 4];
    } else {
        const float* __restrict__ fb = feat + (size_t)b * C * N;
        #pragma unroll
        for (int g = 0; g < 16; ++g) {
            v[g].x = fb[(size_t)(4 * g + 0) * N + id];
            v[g].y = fb[(size_t)(4 * g + 1) * N + id];
            v[g].z = fb[(size_t)(4 * g + 2) * N + id];
            v[g].w = fb[(size_t)(4 * g + 3) * N + id];
        }
    }

    out[obase]      = pxy.x - qx;
    out[obase + SK] = pxy.y - qy;
    #pragma unroll
    for (int g = 0; g < 16; ++g) {
        out[obase + (size_t)(2 + 4 * g + 0) * SK] = v[g].x;
        out[obase + (size_t)(2 + 4 * g + 1) * SK] = v[g].y;
        out[obase + (size_t)(2 + 4 * g + 2) * SK] = v[g].z;
        out[obase + (size_t)(2 + 4 * g + 3) * SK] = v[g].w;
    }
}

extern "C" void kernel_launch(void* const* d_in, const int* in_sizes, int n_in,
                              void* d_out, int out_size, void* d_ws, size_t ws_size,
                              hipStream_t stream) {
    const float* xyz       = (const float*)d_in[0];
    const float* new_xyz   = (const float*)d_in[1];
    const float* feat      = (const float*)d_in[2];
    const int*   pointsnum = (const int*)d_in[3];
    float*       out       = (float*)d_out;

    const size_t need = (size_t)B * N * C * sizeof(float);
    if (ws_size >= need) {
        float* ft = (float*)d_ws;
        transpose_kernel<<<dim3(N / 64, B), 256, 0, stream>>>(feat, ft);
        qag_kernel<true><<<B * S / 4, 256, 0, stream>>>(xyz, new_xyz, feat, ft, pointsnum, out);
    } else {
        qag_kernel<false><<<B * S / 4, 256, 0, stream>>>(xyz, new_xyz, feat, nullptr, pointsnum, out);
    }
}

// Round 4
// 59.557 us; speedup vs baseline: 1.6789x; 1.0197x over previous
//
#include <hip/hip_runtime.h>
#include <stdint.h>

#define B 4
#define N 16384
#define S 2048
#define C 64
#define K 64
#define OC 66
#define R2 0.01f

typedef float f32x4 __attribute__((ext_vector_type(4)));   // nontemporal-safe

// ---------------------------------------------------------------------------
// Kernel 1: transpose features (B,C,N) -> ft (B,N,C) so that a selected
// point's 64 channels are contiguous (256B) for the gather.
// ---------------------------------------------------------------------------
__global__ __launch_bounds__(256) void transpose_kernel(const float* __restrict__ f,
                                                        float* __restrict__ ft) {
    __shared__ float tile[64 * 65];   // +1 pad -> conflict-free transpose read
    const int n0 = blockIdx.x * 64;
    const int b  = blockIdx.y;
    const int t  = threadIdx.x;

    const int nl = t & 63, cl = t >> 6;
    #pragma unroll
    for (int cc = cl; cc < 64; cc += 4) {
        // streamed once -> nontemporal read
        tile[cc * 65 + nl] = __builtin_nontemporal_load(&f[((size_t)b * C + cc) * N + n0 + nl]);
    }
    __syncthreads();

    const int cl2 = t & 63, nl2 = t >> 6;
    #pragma unroll
    for (int nn = nl2; nn < 64; nn += 4) {
        // normal store: ft is re-read by the gather, keep it cacheable
        ft[((size_t)b * N + n0 + nn) * C + cl2] = tile[cl2 * 65 + nn];
    }
}

// ---------------------------------------------------------------------------
// Kernel 2: fused ball-query + group + concat.
// One wave per query, 4 consecutive queries (same b) per block. Scan is
// wave-independent (no barriers). Gather is 64B-per-point chunks (full cache
// line). Stores are staged through LDS so every store instruction writes a
// 1 KB CONTIGUOUS run (4 queries x 64 k for one channel) -> DRAM-friendly.
// ---------------------------------------------------------------------------
template <bool USE_T>
__global__ __launch_bounds__(256) void qag_kernel(const float* __restrict__ xyz,
                                                  const float* __restrict__ new_xyz,
                                                  const float* __restrict__ feat,
                                                  const float* __restrict__ ft,
                                                  const int* __restrict__ pointsnum,
                                                  float* __restrict__ out) {
    __shared__ int   s_idx[4][K];      // per-wave index list
    __shared__ float tile[4][16][K];   // [q][c-in-chunk][k]  (16 KB)

    const int t    = threadIdx.x;
    const int lane = t & 63;
    const int wu   = __builtin_amdgcn_readfirstlane(t >> 6);  // wave id (SGPR)
    const int q0   = blockIdx.x * 4;       // scalar
    const int b    = q0 >> 11;             // / S (S=2048); uniform per block
    const int s0   = q0 & (S - 1);
    const int q    = q0 + wu;              // this wave's query (SGPR)
    const int s    = s0 + wu;

    const float qx = new_xyz[(size_t)q * 2 + 0];
    const float qy = new_xyz[(size_t)q * 2 + 1];
    const float* __restrict__ xb = xyz + (size_t)b * N * 2;

    // ---- Phase 1: ordered ball-query scan (per-wave, 4 loads in flight) ----
    int pn = pointsnum[b];
    pn = pn < 0 ? 0 : (pn > N ? N : pn);
    int cnt = 0;
    for (int base = 0; base < pn && cnt < K; base += 256) {
        float2 p[4];
        #pragma unroll
        for (int u = 0; u < 4; ++u) {
            int i  = base + u * 64 + lane;
            int ic = i < N ? i : N - 1;              // always-valid address
            p[u] = *(const float2*)&xb[(size_t)ic * 2];
        }
        #pragma unroll
        for (int u = 0; u < 4; ++u) {
            const int i = base + u * 64 + lane;
            bool ok = false;
            if (i < pn) {
                // match numpy f32 rounding exactly: no FMA contraction
                const float dx = __fsub_rn(qx, p[u].x);
                const float dy = __fsub_rn(qy, p[u].y);
                const float d2 = __fadd_rn(__fmul_rn(dx, dx), __fmul_rn(dy, dy));
                ok = d2 < R2;
            }
            const unsigned long long m = __ballot(ok);
            if (ok) {
                const int pos = cnt + __popcll(m & ((1ull << lane) - 1ull));
                if (pos < K) s_idx[wu][pos] = i;
            }
            cnt += __popcll(m);
        }
    }
    const int found = cnt < K ? cnt : K;
    const int first = (found > 0) ? s_idx[wu][0] : 0;   // pad value (0 if none)
    const int id    = (lane < found) ? s_idx[wu][lane] : first;

    // ---- channels 0,1: grouped_xyz = xyz[id] - new_xyz[s] (direct 256B) ----
    const size_t SK = (size_t)S * K;
    const float2 pxy = *(const float2*)&xb[(size_t)id * 2];
    {
        float* ob = out + ((size_t)b * OC) * SK + (size_t)s * K;
        __builtin_nontemporal_store(pxy.x - qx, ob + lane);
        __builtin_nontemporal_store(pxy.y - qy, ob + SK + lane);
    }

    // ---- Phase 2: gather 16-channel chunks, stage in LDS, 1KB stores ----
    const float* __restrict__ row = USE_T ? (ft + ((size_t)b * N + id) * C) : nullptr;
    const float* __restrict__ fb  = feat + (size_t)b * C * N;
    const int ql = lane >> 4;              // store-phase: query sub-index 0..3
    const int kq = (lane & 15) * 4;        // store-phase: k base

    #pragma unroll
    for (int cc = 0; cc < 4; ++cc) {       // channels 16*cc .. 16*cc+15
        float4 g0, g1, g2, g3;
        if (USE_T) {
            const float4* r4 = (const float4*)(row + 16 * cc);
            g0 = r4[0]; g1 = r4[1]; g2 = r4[2]; g3 = r4[3];   // 64B = 1 line
        } else {
            const int c0 = 16 * cc;
            g0.x = fb[(size_t)(c0 +  0) * N + id]; g0.y = fb[(size_t)(c0 +  1) * N + id];
            g0.z = fb[(size_t)(c0 +  2) * N + id]; g0.w = fb[(size_t)(c0 +  3) * N + id];
            g1.x = fb[(size_t)(c0 +  4) * N + id]; g1.y = fb[(size_t)(c0 +  5) * N + id];
            g1.z = fb[(size_t)(c0 +  6) * N + id]; g1.w = fb[(size_t)(c0 +  7) * N + id];
            g2.x = fb[(size_t)(c0 +  8) * N + id]; g2.y = fb[(size_t)(c0 +  9) * N + id];
            g2.z = fb[(size_t)(c0 + 10) * N + id]; g2.w = fb[(size_t)(c0 + 11) * N + id];
            g3.x = fb[(size_t)(c0 + 12) * N + id]; g3.y = fb[(size_t)(c0 + 13) * N + id];
            g3.z = fb[(size_t)(c0 + 14) * N + id]; g3.w = fb[(size_t)(c0 + 15) * N + id];
        }

        __syncthreads();   // previous chunk's tile reads are done
        // lane = k; banks = lane%32 -> 2 lanes/bank (free)
        tile[wu][ 0][lane] = g0.x; tile[wu][ 1][lane] = g0.y;
        tile[wu][ 2][lane] = g0.z; tile[wu][ 3][lane] = g0.w;
        tile[wu][ 4][lane] = g1.x; tile[wu][ 5][lane] = g1.y;
        tile[wu][ 6][lane] = g1.z; tile[wu][ 7][lane] = g1.w;
        tile[wu][ 8][lane] = g2.x; tile[wu][ 9][lane] = g2.y;
        tile[wu][10][lane] = g2.z; tile[wu][11][lane] = g2.w;
        tile[wu][12][lane] = g3.x; tile[wu][13][lane] = g3.y;
        tile[wu][14][lane] = g3.z; tile[wu][15][lane] = g3.w;
        __syncthreads();

        // each wave stores 4 channels; one instr = 64 lanes x float4 = 1 KB
        // contiguous: out[b][2+c][s0 + (lane>>4)][(lane&15)*4 ..+3]
        #pragma unroll
        for (int j = 0; j < 4; ++j) {
            const int c16 = 4 * wu + j;                 // channel within chunk
            const int c   = 16 * cc + c16;              // global feature chan
            f32x4 vv = *(const f32x4*)&tile[ql][c16][kq];
            float* bp = out + ((size_t)b * OC + 2 + c) * SK + (size_t)s0 * K;
            __builtin_nontemporal_store(vv, ((f32x4*)bp) + lane);
        }
    }
}

extern "C" void kernel_launch(void* const* d_in, const int* in_sizes, int n_in,
                              void* d_out, int out_size, void* d_ws, size_t ws_size,
                              hipStream_t stream) {
    const float* xyz       = (const float*)d_in[0];
    const float* new_xyz   = (const float*)d_in[1];
    const float* feat      = (const float*)d_in[2];
    const int*   pointsnum = (const int*)d_in[3];
    float*       out       = (float*)d_out;

    const size_t need = (size_t)B * N * C * sizeof(float);
    if (ws_size >= need) {
        float* ft = (float*)d_ws;
        transpose_kernel<<<dim3(N / 64, B), 256, 0, stream>>>(feat, ft);
        qag_kernel<true><<<B * S / 4, 256, 0, stream>>>(xyz, new_xyz, feat, ft, pointsnum, out);
    } else {
        qag_kernel<false><<<B * S / 4, 256, 0, stream>>>(xyz, new_xyz, feat, nullptr, pointsnum, out);
    }
}

// Round 5
// 55.907 us; speedup vs baseline: 1.7886x; 1.0653x over previous
//
#include <hip/hip_runtime.h>
#include <stdint.h>

#define B 4
#define N 16384
#define S 2048
#define C 64
#define K 64
#define OC 66
#define R2 0.01f
#define NXCD 8

typedef float f32x4 __attribute__((ext_vector_type(4)));   // nontemporal-safe

// ---------------------------------------------------------------------------
// Kernel 1: transpose features (B,C,N) -> ft (B,N,C) so that a selected
// point's 64 channels are contiguous (256B) for the gather.
// ---------------------------------------------------------------------------
__global__ __launch_bounds__(256) void transpose_kernel(const float* __restrict__ f,
                                                        float* __restrict__ ft) {
    __shared__ float tile[64 * 65];   // +1 pad -> conflict-free transpose read
    const int n0 = blockIdx.x * 64;
    const int b  = blockIdx.y;
    const int t  = threadIdx.x;

    const int nl = t & 63, cl = t >> 6;
    #pragma unroll
    for (int cc = cl; cc < 64; cc += 4) {
        // streamed once -> nontemporal read
        tile[cc * 65 + nl] = __builtin_nontemporal_load(&f[((size_t)b * C + cc) * N + n0 + nl]);
    }
    __syncthreads();

    const int cl2 = t & 63, nl2 = t >> 6;
    #pragma unroll
    for (int nn = nl2; nn < 64; nn += 4) {
        // normal store: ft is re-read by the gather, keep it cacheable
        ft[((size_t)b * N + n0 + nn) * C + cl2] = tile[cl2 * 65 + nn];
    }
}

// ---------------------------------------------------------------------------
// Kernel 2: fused ball-query + group + concat.
// One wave per query, 4 consecutive queries (same b) per block.
// XCD-aware swizzle: each XCD owns 1024 CONSECUTIVE queries (half a batch),
// so its gather working set is one batch's 4.2 MB ft region (~= 4 MB L2)
// instead of all 16.8 MB -> gathers become L2 hits instead of L3 traffic.
// ---------------------------------------------------------------------------
template <bool USE_T>
__global__ __launch_bounds__(256) void qag_kernel(const float* __restrict__ xyz,
                                                  const float* __restrict__ new_xyz,
                                                  const float* __restrict__ feat,
                                                  const float* __restrict__ ft,
                                                  const int* __restrict__ pointsnum,
                                                  float* __restrict__ out) {
    __shared__ int   s_idx[4][K];      // per-wave index list
    __shared__ float tile[4][16][K];   // [q][c-in-chunk][k]  (16 KB)

    const int t    = threadIdx.x;
    const int lane = t & 63;
    const int wu   = __builtin_amdgcn_readfirstlane(t >> 6);  // wave id (SGPR)

    // bijective XCD swizzle: nwg = B*S/4 = 2048, 2048 % 8 == 0
    const int nwg = (B * S) / 4;
    const int bid = blockIdx.x;
    const int swz = (bid & (NXCD - 1)) * (nwg / NXCD) + (bid >> 3);

    const int q0   = swz * 4;              // scalar
    const int b    = q0 >> 11;             // / S (S=2048); uniform per block
    const int s0   = q0 & (S - 1);
    const int q    = q0 + wu;              // this wave's query (SGPR)
    const int s    = s0 + wu;

    const float qx = new_xyz[(size_t)q * 2 + 0];
    const float qy = new_xyz[(size_t)q * 2 + 1];
    const float* __restrict__ xb = xyz + (size_t)b * N * 2;

    // ---- Phase 1: ordered ball-query scan (per-wave, 4 loads in flight) ----
    int pn = pointsnum[b];
    pn = pn < 0 ? 0 : (pn > N ? N : pn);
    int cnt = 0;
    for (int base = 0; base < pn && cnt < K; base += 256) {
        float2 p[4];
        #pragma unroll
        for (int u = 0; u < 4; ++u) {
            int i  = base + u * 64 + lane;
            int ic = i < N ? i : N - 1;              // always-valid address
            p[u] = *(const float2*)&xb[(size_t)ic * 2];
        }
        #pragma unroll
        for (int u = 0; u < 4; ++u) {
            const int i = base + u * 64 + lane;
            bool ok = false;
            if (i < pn) {
                // match numpy f32 rounding exactly: no FMA contraction
                const float dx = __fsub_rn(qx, p[u].x);
                const float dy = __fsub_rn(qy, p[u].y);
                const float d2 = __fadd_rn(__fmul_rn(dx, dx), __fmul_rn(dy, dy));
                ok = d2 < R2;
            }
            const unsigned long long m = __ballot(ok);
            if (ok) {
                const int pos = cnt + __popcll(m & ((1ull << lane) - 1ull));
                if (pos < K) s_idx[wu][pos] = i;
            }
            cnt += __popcll(m);
        }
    }
    const int found = cnt < K ? cnt : K;
    const int first = (found > 0) ? s_idx[wu][0] : 0;   // pad value (0 if none)
    const int id    = (lane < found) ? s_idx[wu][lane] : first;

    // ---- channels 0,1: grouped_xyz = xyz[id] - new_xyz[s] (direct 256B) ----
    const size_t SK = (size_t)S * K;
    const float2 pxy = *(const float2*)&xb[(size_t)id * 2];
    {
        float* ob = out + ((size_t)b * OC) * SK + (size_t)s * K;
        __builtin_nontemporal_store(pxy.x - qx, ob + lane);
        __builtin_nontemporal_store(pxy.y - qy, ob + SK + lane);
    }

    // ---- Phase 2: gather 16-channel chunks, stage in LDS, 1KB stores ----
    const float* __restrict__ row = USE_T ? (ft + ((size_t)b * N + id) * C) : nullptr;
    const float* __restrict__ fb  = feat + (size_t)b * C * N;
    const int ql = lane >> 4;              // store-phase: query sub-index 0..3
    const int kq = (lane & 15) * 4;        // store-phase: k base

    #pragma unroll
    for (int cc = 0; cc < 4; ++cc) {       // channels 16*cc .. 16*cc+15
        float4 g0, g1, g2, g3;
        if (USE_T) {
            const float4* r4 = (const float4*)(row + 16 * cc);
            g0 = r4[0]; g1 = r4[1]; g2 = r4[2]; g3 = r4[3];   // 64B = 1 line
        } else {
            const int c0 = 16 * cc;
            g0.x = fb[(size_t)(c0 +  0) * N + id]; g0.y = fb[(size_t)(c0 +  1) * N + id];
            g0.z = fb[(size_t)(c0 +  2) * N + id]; g0.w = fb[(size_t)(c0 +  3) * N + id];
            g1.x = fb[(size_t)(c0 +  4) * N + id]; g1.y = fb[(size_t)(c0 +  5) * N + id];
            g1.z = fb[(size_t)(c0 +  6) * N + id]; g1.w = fb[(size_t)(c0 +  7) * N + id];
            g2.x = fb[(size_t)(c0 +  8) * N + id]; g2.y = fb[(size_t)(c0 +  9) * N + id];
            g2.z = fb[(size_t)(c0 + 10) * N + id]; g2.w = fb[(size_t)(c0 + 11) * N + id];
            g3.x = fb[(size_t)(c0 + 12) * N + id]; g3.y = fb[(size_t)(c0 + 13) * N + id];
            g3.z = fb[(size_t)(c0 + 14) * N + id]; g3.w = fb[(size_t)(c0 + 15) * N + id];
        }

        __syncthreads();   // previous chunk's tile reads are done
        // lane = k; banks = lane%32 -> 2 lanes/bank (free)
        tile[wu][ 0][lane] = g0.x; tile[wu][ 1][lane] = g0.y;
        tile[wu][ 2][lane] = g0.z; tile[wu][ 3][lane] = g0.w;
        tile[wu][ 4][lane] = g1.x; tile[wu][ 5][lane] = g1.y;
        tile[wu][ 6][lane] = g1.z; tile[wu][ 7][lane] = g1.w;
        tile[wu][ 8][lane] = g2.x; tile[wu][ 9][lane] = g2.y;
        tile[wu][10][lane] = g2.z; tile[wu][11][lane] = g2.w;
        tile[wu][12][lane] = g3.x; tile[wu][13][lane] = g3.y;
        tile[wu][14][lane] = g3.z; tile[wu][15][lane] = g3.w;
        __syncthreads();

        // each wave stores 4 channels; one instr = 64 lanes x float4 = 1 KB
        // contiguous: out[b][2+c][s0 + (lane>>4)][(lane&15)*4 ..+3]
        #pragma unroll
        for (int j = 0; j < 4; ++j) {
            const int c16 = 4 * wu + j;                 // channel within chunk
            const int c   = 16 * cc + c16;              // global feature chan
            f32x4 vv = *(const f32x4*)&tile[ql][c16][kq];
            float* bp = out + ((size_t)b * OC + 2 + c) * SK + (size_t)s0 * K;
            __builtin_nontemporal_store(vv, ((f32x4*)bp) + lane);
        }
    }
}

extern "C" void kernel_launch(void* const* d_in, const int* in_sizes, int n_in,
                              void* d_out, int out_size, void* d_ws, size_t ws_size,
                              hipStream_t stream) {
    const float* xyz       = (const float*)d_in[0];
    const float* new_xyz   = (const float*)d_in[1];
    const float* feat      = (const float*)d_in[2];
    const int*   pointsnum = (const int*)d_in[3];
    float*       out       = (float*)d_out;

    const size_t need = (size_t)B * N * C * sizeof(float);
    if (ws_size >= need) {
        float* ft = (float*)d_ws;
        transpose_kernel<<<dim3(N / 64, B), 256, 0, stream>>>(feat, ft);
        qag_kernel<true><<<B * S / 4, 256, 0, stream>>>(xyz, new_xyz, feat, ft, pointsnum, out);
    } else {
        qag_kernel<false><<<B * S / 4, 256, 0, stream>>>(xyz, new_xyz, feat, nullptr, pointsnum, out);
    }
}